// Round 4
// baseline (749.694 us; speedup 1.0000x reference)
//
#include <hip/hip_runtime.h>
#include <hip/hip_bf16.h>
#include <math.h>

typedef __hip_bfloat16 bf16;

#define AFEA 128          // atom_fea_len
#define NBRF 41           // nbr_fea_len
#define IN2 297           // 2A + NBR
#define KP 320            // MFMA-padded K (10 chunks of 32)
#define TSTR 328          // LDS A-tile row stride in shorts (R0-proven pad)
#define ROWS 64           // A-tile rows
#define P1 64             // bn1 stat partial copies
#define P2 16             // bn2 stat partial copies
#define LSP 130           // ls row pad (floats): q-stride 520%32=8 -> max 2-way conflicts

typedef __attribute__((ext_vector_type(8))) short bf16x8;   // MFMA A/B frag
typedef __attribute__((ext_vector_type(4))) float f32x4;    // MFMA C/D frag

__device__ __forceinline__ unsigned short bfbits(float x) {
    bf16 h = __float2bfloat16(x);
    return *(unsigned short*)&h;
}
__device__ __forceinline__ unsigned int pack2(float x, float y) {
    return (unsigned int)bfbits(x) | ((unsigned int)bfbits(y) << 16);
}
__device__ __forceinline__ float blo(unsigned int u) { return __uint_as_float(u << 16); }
__device__ __forceinline__ float bhi(unsigned int u) { return __uint_as_float(u & 0xffff0000u); }
__device__ __forceinline__ float leakyf(float x) { return x >= 0.f ? x : 0.01f * x; }
__device__ __forceinline__ float sigmoid_fast(float x) { return 1.f / (1.f + __expf(-x)); }
__device__ __forceinline__ float softplus_fast(float x) {
    return fmaxf(x, 0.f) + __logf(1.f + __expf(-fabsf(x)));
}

// conv-set column permutation: GEMM slot -> actual channel. Wave w holds filter
// channels w*32..w*32+31 as ct 0-1 and their paired core channels (+128) as ct 2-3,
// so sigmoid(filter)*leaky(core) is thread-local in the gate epilogue.
__device__ __forceinline__ int permch(int slot) {
    int w = slot >> 6, ct = (slot >> 4) & 3, m = slot & 15;
    int base = w * 32 + (ct & 1) * 16 + m;
    return (ct < 2) ? base : 128 + base;
}

// ---------------- nbr_fea (f32 [NM][41]) -> nbr16 (bf16 [NM][64], zero-padded) ----------------
__global__ void nbr16_kernel(const float* __restrict__ nbr, unsigned short* __restrict__ nbr16,
                             int NM)
{
    int i = blockIdx.x * blockDim.x + threadIdx.x;
    if (i >= NM * 64) return;
    int k = i & 63, e = i >> 6;
    nbr16[i] = (k < NBRF) ? bfbits(nbr[(size_t)e * NBRF + k]) : 0;
}

// ---------------- embedding: af = atom_fea @ emb_W.T + emb_b (W staged in LDS) ----------------
__global__ __launch_bounds__(256) void embed_kernel(
    const float* __restrict__ xf, const float* __restrict__ W,
    const float* __restrict__ b, float* __restrict__ af,
    unsigned short* __restrict__ af16, int N)
{
    __shared__ float W_s[92 * 128];
    __shared__ float xs[16 * 92];
    int t = threadIdx.x;
    int n0 = blockIdx.x * 16;
    for (int i = t; i < 92 * 128; i += 256) {
        int o = i / 92, k = i - o * 92;
        W_s[k * 128 + o] = W[i];
    }
    for (int i = t; i < 16 * 92; i += 256) {
        int a = i / 92, k = i - a * 92;
        int n = n0 + a;
        xs[i] = (n < N) ? xf[(size_t)n * 92 + k] : 0.f;
    }
    __syncthreads();
    int o = t & 127, h = t >> 7;
    float bias = b[o];
    for (int a = h; a < 16; a += 2) {
        int n = n0 + a;
        if (n >= N) break;
        float acc = bias;
        const float* xr = xs + a * 92;
        #pragma unroll 4
        for (int k = 0; k < 92; k++) acc += xr[k] * W_s[k * 128 + o];
        af[(size_t)n * AFEA + o] = acc;
        af16[(size_t)n * AFEA + o] = bfbits(acc);
    }
}

// ---------------- prep_all: zero stat partials + build all 4 Wb sets upfront ----------------
// Wb4: [set][KP/32][256][32] bf16. Sets 0-2 = conv i with permch column pairing;
// set 3 = heads, identity (cols 0-127 dist_W, 128-255 const_W).
__global__ void prep_all_kernel(const float* __restrict__ convs_W,
                                const float* __restrict__ dist_W,
                                const float* __restrict__ const_W,
                                unsigned short* __restrict__ Wb4,
                                float* __restrict__ zbuf, int nz)
{
    int i = blockIdx.x * blockDim.x + threadIdx.x;
    if (i < nz) zbuf[i] = 0.f;
    if (i >= 4 * KP * 256) return;
    int s = i / (KP * 256);
    int r = i - s * (KP * 256);
    int t32 = r & 31;
    int c = (r >> 5) & 255;
    int kc = r >> 13;
    int k = kc * 32 + t32;
    float v = 0.f;
    if (k < IN2) {
        if (s < 3) v = convs_W[((size_t)s * 256 + permch(c)) * IN2 + k];
        else       v = (c < 128) ? dist_W[(size_t)c * IN2 + k]
                                 : const_W[(size_t)(c - 128) * IN2 + k];
    }
    Wb4[i] = bfbits(v);
}

// ---------------- shared GEMM core (R0-proven): stage A-tile, MFMA K-loop -> acc ----------------
__device__ __forceinline__ void gemm_core(
    const unsigned short* __restrict__ af16, const unsigned short* __restrict__ nbr16,
    const int* __restrict__ idx, const unsigned short* __restrict__ Wb,
    unsigned short* a_tile, int e0, int M, int t, f32x4 (&acc)[4][4])
{
    const int l = t & 63, w = t >> 6;
    const int m16 = l & 15, q = l >> 4;
    const unsigned short* bbase = Wb + (size_t)(w * 64 + m16) * 32 + q * 8;

    // stage A-tile: 64 rows, 4 threads/row, all 16B vector ops
    {
        int row = t >> 2, p = t & 3;
        int e = e0 + row;
        int n = e / M;
        int j = idx[e];
        const uint4* srcn = (const uint4*)(af16 + (size_t)n * AFEA);
        const uint4* srcj = (const uint4*)(af16 + (size_t)j * AFEA);
        const uint4* srcb = (const uint4*)(nbr16 + (size_t)e * 64);
        uint4* dst = (uint4*)(a_tile + row * TSTR);
        #pragma unroll
        for (int u = 0; u < 4; u++) dst[p + 4 * u] = srcn[p + 4 * u];
        #pragma unroll
        for (int u = 0; u < 4; u++) dst[16 + p + 4 * u] = srcj[p + 4 * u];
        #pragma unroll
        for (int u = 0; u < 2; u++) dst[32 + p + 4 * u] = srcb[p + 4 * u];
    }

    // B prefetch (kc=0,1) issued before barrier
    bf16x8 bcur[4], bnxt[4];
    #pragma unroll
    for (int ct = 0; ct < 4; ct++)
        bcur[ct] = *(const bf16x8*)(bbase + ct * 512);
    #pragma unroll
    for (int ct = 0; ct < 4; ct++)
        bnxt[ct] = *(const bf16x8*)(bbase + 8192 + ct * 512);

    __syncthreads();

    #pragma unroll
    for (int rt = 0; rt < 4; rt++)
        #pragma unroll
        for (int ct = 0; ct < 4; ct++) acc[rt][ct] = (f32x4)0.f;

    const unsigned short* abase = a_tile + m16 * TSTR + q * 8;

    #pragma unroll
    for (int kc = 0; kc < KP / 32; kc++) {
        bf16x8 a[4], b2[4];
        if (kc < KP / 32 - 2) {
            #pragma unroll
            for (int ct = 0; ct < 4; ct++)
                b2[ct] = *(const bf16x8*)(bbase + (kc + 2) * 8192 + ct * 512);
        }
        #pragma unroll
        for (int rt = 0; rt < 4; rt++)
            a[rt] = *(const bf16x8*)(abase + rt * 16 * TSTR + kc * 32);
        #pragma unroll
        for (int rt = 0; rt < 4; rt++)
            #pragma unroll
            for (int ct = 0; ct < 4; ct++)
                acc[rt][ct] = __builtin_amdgcn_mfma_f32_16x16x32_bf16(
                    a[rt], bcur[ct], acc[rt][ct], 0, 0, 0);
        if (kc < KP / 32 - 1) {
            #pragma unroll
            for (int ct = 0; ct < 4; ct++) bcur[ct] = bnxt[ct];
        }
        if (kc < KP / 32 - 2) {
            #pragma unroll
            for (int ct = 0; ct < 4; ct++) bnxt[ct] = b2[ct];
        }
    }
}

// ---------------- pass1: GEMM -> bn1 stats only (NO g_t stores); also zeroes summed ----------------
__global__ __launch_bounds__(256, 3) void gemm_stats_kernel(
    const unsigned short* __restrict__ af16, const unsigned short* __restrict__ nbr16,
    const int* __restrict__ idx, const unsigned short* __restrict__ Wb,
    const float* __restrict__ bias256, float* __restrict__ part1,
    float* __restrict__ summed, int NM, int M, int nsum)
{
    __shared__ __align__(16) unsigned short a_tile[ROWS * TSTR];
    int t = threadIdx.x;
    for (int i = blockIdx.x * 256 + t; i < nsum; i += gridDim.x * 256) summed[i] = 0.f;

    f32x4 acc[4][4];
    gemm_core(af16, nbr16, idx, Wb, a_tile, blockIdx.x * ROWS, M, t, acc);

    const int l = t & 63, w = t >> 6, m16 = l & 15, q = l >> 4;
    float* pp = part1 + (size_t)(blockIdx.x & (P1 - 1)) * 512;
    #pragma unroll
    for (int ct = 0; ct < 4; ct++) {
        int col = w * 64 + ct * 16 + m16;
        float bias = bias256[permch(col)];
        float ps = 0.f, pq = 0.f;
        #pragma unroll
        for (int rt = 0; rt < 4; rt++) {
            float v0 = acc[rt][ct][0] + bias;
            float v1 = acc[rt][ct][1] + bias;
            float v2 = acc[rt][ct][2] + bias;
            float v3 = acc[rt][ct][3] + bias;
            ps += (v0 + v1) + (v2 + v3);
            pq += (v0 * v0 + v1 * v1) + (v2 * v2 + v3 * v3);
        }
        ps += __shfl_xor(ps, 16); ps += __shfl_xor(ps, 32);
        pq += __shfl_xor(pq, 16); pq += __shfl_xor(pq, 32);
        if (q == 0) {
            atomicAdd(&pp[col], ps);
            atomicAdd(&pp[256 + col], pq);
        }
    }
}

// ---------------- bn1 finalize: part1 -> aff[512] (slot-indexed); zeroes part2 ----------------
__global__ __launch_bounds__(256) void bn1fin_kernel(
    const float* __restrict__ part1, const float* __restrict__ gamma,
    const float* __restrict__ beta, float* __restrict__ aff,
    float* __restrict__ part2, float cnt1)
{
    int t = threadIdx.x;
    #pragma unroll
    for (int k = 0; k < P2; k++) part2[k * 256 + t] = 0.f;
    float s = 0.f, qq = 0.f;
    #pragma unroll 8
    for (int p = 0; p < P1; p++) {
        s  += part1[(size_t)p * 512 + t];
        qq += part1[(size_t)p * 512 + 256 + t];
    }
    float mean = s / cnt1;
    float var = fmaxf(qq / cnt1 - mean * mean, 0.f);
    int ch = permch(t);
    float a = gamma[ch] * rsqrtf(var + 1e-5f);
    aff[t] = a;
    aff[256 + t] = beta[ch] - mean * a;
}

// ---------------- pass2: recompute GEMM + fused bn1+gate+atom-sum (no g_t at all) ----------------
__global__ __launch_bounds__(256, 3) void gemm_gate_kernel(
    const unsigned short* __restrict__ af16, const unsigned short* __restrict__ nbr16,
    const int* __restrict__ idx, const unsigned short* __restrict__ Wb,
    const float* __restrict__ bias256, const float* __restrict__ aff,
    float* __restrict__ summed, int NM, int M)
{
    __shared__ __align__(16) unsigned short a_tile[ROWS * TSTR];
    float* ls = (float*)a_tile;   // [ROWS][LSP] f32 = 33280 B, reused after MFMA
    int t = threadIdx.x;
    const int e0 = blockIdx.x * ROWS;

    f32x4 acc[4][4];
    gemm_core(af16, nbr16, idx, Wb, a_tile, e0, M, t, acc);

    const int l = t & 63, w = t >> 6, m16 = l & 15, q = l >> 4;

    __syncthreads();   // all waves done reading a_tile -> safe to reuse as ls

    #pragma unroll
    for (int ct = 0; ct < 2; ct++) {
        int sf  = w * 64 + ct * 16 + m16;   // filter slot; paired core slot = sf+32
        int fch = w * 32 + ct * 16 + m16;   // filter channel 0..127
        float aF = aff[sf],      cF = aff[256 + sf];
        float aC = aff[sf + 32], cC = aff[256 + sf + 32];
        cF = fmaf(aF, bias256[fch], cF);         // fold bias into affine offset
        cC = fmaf(aC, bias256[128 + fch], cC);
        #pragma unroll
        for (int rt = 0; rt < 4; rt++) {
            int rbase = rt * 16 + q * 4;
            #pragma unroll
            for (int j = 0; j < 4; j++) {
                float zf = fmaf(aF, acc[rt][ct][j], cF);
                float zc = fmaf(aC, acc[rt][ct + 2][j], cC);
                ls[(rbase + j) * LSP + fch] = sigmoid_fast(zf) * leakyf(zc);
            }
        }
    }
    __syncthreads();

    // per-atom reduction over this tile's rows; atomicAdd boundary-safe across tiles
    int nfirst = e0 / M;
    int nlast  = (e0 + ROWS - 1) / M;
    int ntasks = (nlast - nfirst + 1) * 128;
    for (int task = t; task < ntasks; task += 256) {
        int ai = task >> 7, c = task & 127;
        int n = nfirst + ai;
        int lo = n * M - e0;           if (lo < 0) lo = 0;
        int hi = n * M + M - 1 - e0;   if (hi > ROWS - 1) hi = ROWS - 1;
        float s = 0.f;
        for (int r = lo; r <= hi; r++) s += ls[r * LSP + c];
        atomicAdd(&summed[(size_t)n * AFEA + c], s);
    }
}

// ---------------- sumstats: summed -> bn2 stat partials (part2) ----------------
__global__ __launch_bounds__(256) void sumstats_kernel(
    const float* __restrict__ summed, float* __restrict__ part2, int N)
{
    int t = threadIdx.x;
    int c = t & 127, h = t >> 7;
    int n0 = blockIdx.x * 128;
    float s = 0.f, qq = 0.f;
    for (int a = h; a < 128; a += 2) {
        int n = n0 + a;
        if (n >= N) break;
        float v = summed[(size_t)n * AFEA + c];
        s += v; qq += v * v;
    }
    float* pp = part2 + (size_t)(blockIdx.x & (P2 - 1)) * 256;
    atomicAdd(&pp[c], s);
    atomicAdd(&pp[128 + c], qq);
}

// ---------------- residual update: fused bn2-finalize + af = leaky(af + bn2(summed)) ----------------
// Also re-zeroes part1 for the next gemm pass (stream-order safe).
__global__ __launch_bounds__(256) void afup_kernel(
    float* __restrict__ af, unsigned short* __restrict__ af16,
    const float* __restrict__ summed, const float* __restrict__ part2,
    const float* __restrict__ gamma2, const float* __restrict__ beta2,
    float* __restrict__ part1, float cnt2, int total)
{
    __shared__ float a2s[128], c2s[128];
    int t = threadIdx.x;
    if (blockIdx.x < 128) part1[blockIdx.x * 256 + t] = 0.f;
    if (t < 128) {
        float s = 0.f, qq = 0.f;
        #pragma unroll
        for (int p = 0; p < P2; p++) {
            s += part2[(size_t)p * 256 + t];
            qq += part2[(size_t)p * 256 + 128 + t];
        }
        float mean = s / cnt2;
        float var = fmaxf(qq / cnt2 - mean * mean, 0.f);
        float a = gamma2[t] * rsqrtf(var + 1e-5f);
        a2s[t] = a;
        c2s[t] = beta2[t] - mean * a;
    }
    __syncthreads();
    int o = t & 127;
    float a2 = a2s[o], c2 = c2s[o];
    int base = blockIdx.x * 2048 + t;
    #pragma unroll
    for (int k = 0; k < 8; k++) {
        int i = base + k * 256;
        if (i < total) {
            float v = af[i] + a2 * summed[i] + c2;
            v = (v >= 0.f) ? v : 0.01f * v;
            af[i] = v;
            af16[i] = bfbits(v);
        }
    }
}

// ---------------- head-round GEMM (R0 original): g_t stores + bn stats ----------------
__global__ __launch_bounds__(256, 3) void gemm_mfma_kernel(
    const unsigned short* __restrict__ af16, const unsigned short* __restrict__ nbr16,
    const int* __restrict__ idx, const unsigned short* __restrict__ Wb,
    const float* __restrict__ bias_a, const float* __restrict__ bias_b,
    unsigned short* __restrict__ g_t, float* __restrict__ part1,
    int NM, int M)
{
    __shared__ __align__(16) unsigned short a_tile[ROWS * TSTR];
    int t = threadIdx.x;
    const int e0 = blockIdx.x * ROWS;

    f32x4 acc[4][4];
    gemm_core(af16, nbr16, idx, Wb, a_tile, e0, M, t, acc);

    const int l = t & 63, w = t >> 6, m16 = l & 15, q = l >> 4;
    float* pp = part1 + (size_t)(blockIdx.x & (P1 - 1)) * 512;
    #pragma unroll
    for (int ct = 0; ct < 4; ct++) {
        int col = w * 64 + ct * 16 + m16;
        float bias = (col < 128) ? bias_a[col] : bias_b[col - 128];
        float ps = 0.f, pq = 0.f;
        #pragma unroll
        for (int rt = 0; rt < 4; rt++) {
            float v0 = acc[rt][ct][0] + bias;
            float v1 = acc[rt][ct][1] + bias;
            float v2 = acc[rt][ct][2] + bias;
            float v3 = acc[rt][ct][3] + bias;
            ps += (v0 + v1) + (v2 + v3);
            pq += (v0 * v0 + v1 * v1) + (v2 * v2 + v3 * v3);
            uint2 pk;
            pk.x = pack2(v0, v1);
            pk.y = pack2(v2, v3);
            *(uint2*)(g_t + (size_t)col * NM + e0 + rt * 16 + q * 4) = pk;
        }
        ps += __shfl_xor(ps, 16); ps += __shfl_xor(ps, 32);
        pq += __shfl_xor(pq, 16); pq += __shfl_xor(pq, 32);
        if (q == 0) {
            atomicAdd(&pp[col], ps);
            atomicAdd(&pp[256 + col], pq);
        }
    }
}

// ---------------- head: fused bn-finalize + both heads; thread owns 2 bonds ----------------
__global__ __launch_bounds__(256) void head_kernel(
    const unsigned short* __restrict__ gt, const float* __restrict__ part1,
    const float* __restrict__ dbg, const float* __restrict__ cbg,
    const float* __restrict__ dbb, const float* __restrict__ cbb,
    const float* __restrict__ w2d, const float* __restrict__ b2d,
    const float* __restrict__ w2c, const float* __restrict__ b2c,
    const float* __restrict__ pos, const float* __restrict__ off,
    const float* __restrict__ cells, const int* __restrict__ idx,
    float* __restrict__ out, float cnt1, int NM, int M)
{
    __shared__ float a_s[256], c_s[256], w_s[256];
    int t = threadIdx.x;
    {
        float s = 0.f, qq = 0.f;
        #pragma unroll 8
        for (int p = 0; p < P1; p++) {
            s += part1[(size_t)p * 512 + t];
            qq += part1[(size_t)p * 512 + 256 + t];
        }
        float mean = s / cnt1;
        float var = fmaxf(qq / cnt1 - mean * mean, 0.f);
        float g  = (t < 128) ? dbg[t] : cbg[t - 128];
        float be = (t < 128) ? dbb[t] : cbb[t - 128];
        float a = g * rsqrtf(var + 1e-5f);
        a_s[t] = a;
        c_s[t] = be - mean * a;
        w_s[t] = (t < 128) ? w2d[t] : w2c[t - 128];
    }
    __syncthreads();

    int e = blockIdx.x * 512 + t * 2;
    if (e >= NM) return;
    float sd0 = 0.f, sd1 = 0.f, sc0 = 0.f, sc1 = 0.f;
    #pragma unroll 4
    for (int ch = 0; ch < 128; ch++) {
        unsigned int u = *(const unsigned int*)(gt + (size_t)ch * NM + e);
        float a = a_s[ch], c = c_s[ch], wv = w_s[ch];
        sd0 += leakyf(fmaf(a, blo(u), c)) * wv;
        sd1 += leakyf(fmaf(a, bhi(u), c)) * wv;
    }
    #pragma unroll 4
    for (int ch = 128; ch < 256; ch++) {
        unsigned int u = *(const unsigned int*)(gt + (size_t)ch * NM + e);
        float a = a_s[ch], c = c_s[ch], wv = w_s[ch];
        sc0 += softplus_fast(fmaf(a, blo(u), c)) * wv;
        sc1 += softplus_fast(fmaf(a, bhi(u), c)) * wv;
    }
    float dist[2];
    #pragma unroll
    for (int h = 0; h < 2; h++) {
        int eb = e + h;
        int n = eb / M;
        int j = idx[eb];
        float o0 = off[(size_t)eb * 3 + 0];
        float o1 = off[(size_t)eb * 3 + 1];
        float o2 = off[(size_t)eb * 3 + 2];
        float d0 = o0 * cells[0] + o1 * cells[3] + o2 * cells[6] + pos[(size_t)j * 3 + 0] - pos[(size_t)n * 3 + 0];
        float d1 = o0 * cells[1] + o1 * cells[4] + o2 * cells[7] + pos[(size_t)j * 3 + 1] - pos[(size_t)n * 3 + 1];
        float d2 = o0 * cells[2] + o1 * cells[5] + o2 * cells[8] + pos[(size_t)j * 3 + 2] - pos[(size_t)n * 3 + 2];
        dist[h] = sqrtf(d0 * d0 + d1 * d1 + d2 * d2 + 1e-12f);
    }
    float bd = b2d[0], bc = b2c[0];
    float4 o4;
    o4.x = leakyf(sd0 + bd + dist[0]);
    o4.y = softplus_fast(sc0 + bc);
    o4.z = leakyf(sd1 + bd + dist[1]);
    o4.w = softplus_fast(sc1 + bc);
    *(float4*)(out + (size_t)e * 2) = o4;
}

extern "C" void kernel_launch(void* const* d_in, const int* in_sizes, int n_in,
                              void* d_out, int out_size, void* d_ws, size_t ws_size,
                              hipStream_t stream) {
    const float* atom_fea   = (const float*)d_in[0];
    const float* nbr_fea    = (const float*)d_in[1];
    const float* nbr_off    = (const float*)d_in[2];
    const float* atom_pos   = (const float*)d_in[3];
    const float* cells      = (const float*)d_in[4];
    const int*   idx        = (const int*)d_in[5];
    const float* emb_W      = (const float*)d_in[6];
    const float* emb_b      = (const float*)d_in[7];
    const float* convs_W    = (const float*)d_in[8];
    const float* convs_b    = (const float*)d_in[9];
    const float* bn1g       = (const float*)d_in[10];
    const float* bn1b       = (const float*)d_in[11];
    const float* bn2g       = (const float*)d_in[12];
    const float* bn2b       = (const float*)d_in[13];
    const float* dist_W     = (const float*)d_in[14];
    const float* dist_b     = (const float*)d_in[15];
    const float* dist_bn_g  = (const float*)d_in[16];
    const float* dist_bn_b  = (const float*)d_in[17];
    const float* dist2_W    = (const float*)d_in[18];
    const float* dist2_b    = (const float*)d_in[19];
    const float* const_W    = (const float*)d_in[20];
    const float* const_b    = (const float*)d_in[21];
    const float* const_bn_g = (const float*)d_in[22];
    const float* const_bn_b = (const float*)d_in[23];
    const float* const2_W   = (const float*)d_in[24];
    const float* const2_b   = (const float*)d_in[25];

    const int N  = in_sizes[0] / 92;
    const int M  = in_sizes[5] / N;
    const int NM = N * M;

    char* ws = (char*)d_ws;
    size_t off = 0;
    float* af             = (float*)(ws + off); off += (size_t)N * AFEA * 4;
    float* summed         = (float*)(ws + off); off += (size_t)N * AFEA * 4;
    unsigned short* af16  = (unsigned short*)(ws + off); off += (size_t)N * AFEA * 2;
    unsigned short* Wb4   = (unsigned short*)(ws + off); off += (size_t)4 * 256 * KP * 2;
    float* part1          = (float*)(ws + off); off += (size_t)P1 * 512 * 4;
    float* part2          = (float*)(ws + off); off += (size_t)P2 * 256 * 4;
    float* aff            = (float*)(ws + off); off += (size_t)512 * 4;
    unsigned short* g_t   = (unsigned short*)(ws + off); off += (size_t)NM * 256 * 2;
    unsigned short* nbr16 = (unsigned short*)(ws + off); off += (size_t)NM * 64 * 2;

    const int NPART = P1 * 512 + P2 * 256;   // part1+part2 contiguous

    prep_all_kernel<<<(4 * KP * 256 + 255) / 256, 256, 0, stream>>>(
        convs_W, dist_W, const_W, Wb4, part1, NPART);
    nbr16_kernel<<<(NM * 64 + 255) / 256, 256, 0, stream>>>(nbr_fea, nbr16, NM);
    embed_kernel<<<(N + 15) / 16, 256, 0, stream>>>(atom_fea, emb_W, emb_b, af, af16, N);

    const int gblocks = NM / ROWS;
    const int ssblocks = (N + 127) / 128;

    for (int i = 0; i < 3; i++) {
        const unsigned short* Wbi = Wb4 + (size_t)i * KP * 256;
        const float* cb  = convs_b + (size_t)i * 256;
        gemm_stats_kernel<<<gblocks, 256, 0, stream>>>(
            af16, nbr16, idx, Wbi, cb, part1, summed, NM, M, N * AFEA);
        bn1fin_kernel<<<1, 256, 0, stream>>>(
            part1, bn1g + (size_t)i * 256, bn1b + (size_t)i * 256, aff, part2, (float)NM);
        gemm_gate_kernel<<<gblocks, 256, 0, stream>>>(
            af16, nbr16, idx, Wbi, cb, aff, summed, NM, M);
        sumstats_kernel<<<ssblocks, 256, 0, stream>>>(summed, part2, N);
        afup_kernel<<<(N * AFEA + 2047) / 2048, 256, 0, stream>>>(
            af, af16, summed, part2, bn2g + (size_t)i * 128, bn2b + (size_t)i * 128,
            part1, (float)N, N * AFEA);
    }

    // heads: fused 297->256 GEMM (cols 0..127 dist, 128..255 const), R0 path via g_t
    {
        gemm_mfma_kernel<<<gblocks, 256, 0, stream>>>(
            af16, nbr16, idx, Wb4 + (size_t)3 * KP * 256, dist_b, const_b,
            g_t, part1, NM, M);
        head_kernel<<<(NM + 511) / 512, 256, 0, stream>>>(
            g_t, part1, dist_bn_g, const_bn_g, dist_bn_b, const_bn_b,
            dist2_W, dist2_b, const2_W, const2_b,
            atom_pos, nbr_off, cells, idx, (float*)d_out, (float)NM, NM, M);
    }
}

// Round 5
// 665.540 us; speedup vs baseline: 1.1264x; 1.1264x over previous
//
#include <hip/hip_runtime.h>
#include <hip/hip_bf16.h>
#include <math.h>

typedef __hip_bfloat16 bf16;

#define AFEA 128          // atom_fea_len
#define NBRF 41           // nbr_fea_len
#define IN2 297           // 2A + NBR
#define KP 320            // MFMA-padded K (10 chunks of 32)
#define TSTR 328          // LDS A-tile row stride in shorts (R0-proven pad)
#define ROWS 64           // A-tile rows
#define P1 64             // bn1 stat partial copies
#define P2 16             // bn2 stat partial copies

typedef __attribute__((ext_vector_type(8))) short bf16x8;   // MFMA A/B frag
typedef __attribute__((ext_vector_type(4))) float f32x4;    // MFMA C/D frag

__device__ __forceinline__ unsigned short bfbits(float x) {
    bf16 h = __float2bfloat16(x);
    return *(unsigned short*)&h;
}
__device__ __forceinline__ unsigned int pack2(float x, float y) {
    return (unsigned int)bfbits(x) | ((unsigned int)bfbits(y) << 16);
}
__device__ __forceinline__ float blo(unsigned int u) { return __uint_as_float(u << 16); }
__device__ __forceinline__ float bhi(unsigned int u) { return __uint_as_float(u & 0xffff0000u); }
__device__ __forceinline__ float leakyf(float x) { return x >= 0.f ? x : 0.01f * x; }
__device__ __forceinline__ float sigmoid_fast(float x) { return 1.f / (1.f + __expf(-x)); }
__device__ __forceinline__ float softplus_fast(float x) {
    return fmaxf(x, 0.f) + __logf(1.f + __expf(-fabsf(x)));
}

// gated contribution of 2 bonds packed in (fu, cu): sigmoid(bn(filter)) * leaky(bn(core))
__device__ __forceinline__ float gpair(unsigned int fu, unsigned int cu,
                                       float aF, float cF, float aC, float cC) {
    float r = sigmoid_fast(fmaf(aF, blo(fu), cF)) * leakyf(fmaf(aC, blo(cu), cC));
    r += sigmoid_fast(fmaf(aF, bhi(fu), cF)) * leakyf(fmaf(aC, bhi(cu), cC));
    return r;
}

// ---------------- nbr_fea (f32 [NM][41]) -> nbr16 (bf16 [NM][64], zero-padded) ----------------
__global__ void nbr16_kernel(const float* __restrict__ nbr, unsigned short* __restrict__ nbr16,
                             int NM)
{
    int i = blockIdx.x * blockDim.x + threadIdx.x;
    if (i >= NM * 64) return;
    int k = i & 63, e = i >> 6;
    nbr16[i] = (k < NBRF) ? bfbits(nbr[(size_t)e * NBRF + k]) : 0;
}

// ---------------- embedding: af = atom_fea @ emb_W.T + emb_b (W staged in LDS) ----------------
__global__ __launch_bounds__(256) void embed_kernel(
    const float* __restrict__ xf, const float* __restrict__ W,
    const float* __restrict__ b, float* __restrict__ af,
    unsigned short* __restrict__ af16, int N)
{
    __shared__ float W_s[92 * 128];
    __shared__ float xs[16 * 92];
    int t = threadIdx.x;
    int n0 = blockIdx.x * 16;
    for (int i = t; i < 92 * 128; i += 256) {
        int o = i / 92, k = i - o * 92;
        W_s[k * 128 + o] = W[i];
    }
    for (int i = t; i < 16 * 92; i += 256) {
        int a = i / 92, k = i - a * 92;
        int n = n0 + a;
        xs[i] = (n < N) ? xf[(size_t)n * 92 + k] : 0.f;
    }
    __syncthreads();
    int o = t & 127, h = t >> 7;
    float bias = b[o];
    for (int a = h; a < 16; a += 2) {
        int n = n0 + a;
        if (n >= N) break;
        float acc = bias;
        const float* xr = xs + a * 92;
        #pragma unroll 4
        for (int k = 0; k < 92; k++) acc += xr[k] * W_s[k * 128 + o];
        af[(size_t)n * AFEA + o] = acc;
        af16[(size_t)n * AFEA + o] = bfbits(acc);
    }
}

// ---------------- prep_all: zero stat partials + build all 4 Wb sets (identity cols) ----------------
// Wb4 layout: [set 0..3][KP/32][256][32] bf16. Sets 0-2 = conv i; set 3 = heads
// (cols 0-127 dist_W, 128-255 const_W).
__global__ void prep_all_kernel(const float* __restrict__ convs_W,
                                const float* __restrict__ dist_W,
                                const float* __restrict__ const_W,
                                unsigned short* __restrict__ Wb4,
                                float* __restrict__ zbuf, int nz)
{
    int i = blockIdx.x * blockDim.x + threadIdx.x;
    if (i < nz) zbuf[i] = 0.f;
    if (i >= 4 * KP * 256) return;
    int s = i / (KP * 256);
    int r = i - s * (KP * 256);
    int t32 = r & 31;
    int c = (r >> 5) & 255;
    int kc = r >> 13;
    int k = kc * 32 + t32;
    float v = 0.f;
    if (k < IN2) {
        if (s < 3) v = convs_W[((size_t)s * 256 + c) * IN2 + k];
        else       v = (c < 128) ? dist_W[(size_t)c * IN2 + k]
                                 : const_W[(size_t)(c - 128) * IN2 + k];
    }
    Wb4[i] = bfbits(v);
}

// ---------------- shared GEMM core (R0-proven): stage A-tile, MFMA K-loop -> acc ----------------
__device__ __forceinline__ void gemm_core(
    const unsigned short* __restrict__ af16, const unsigned short* __restrict__ nbr16,
    const int* __restrict__ idx, const unsigned short* __restrict__ Wb,
    unsigned short* a_tile, int e0, int M, int t, f32x4 (&acc)[4][4])
{
    const int l = t & 63, w = t >> 6;
    const int m16 = l & 15, q = l >> 4;
    const unsigned short* bbase = Wb + (size_t)(w * 64 + m16) * 32 + q * 8;

    // stage A-tile: 64 rows, 4 threads/row, all 16B vector ops
    {
        int row = t >> 2, p = t & 3;
        int e = e0 + row;
        int n = e / M;
        int j = idx[e];
        const uint4* srcn = (const uint4*)(af16 + (size_t)n * AFEA);
        const uint4* srcj = (const uint4*)(af16 + (size_t)j * AFEA);
        const uint4* srcb = (const uint4*)(nbr16 + (size_t)e * 64);
        uint4* dst = (uint4*)(a_tile + row * TSTR);
        #pragma unroll
        for (int u = 0; u < 4; u++) dst[p + 4 * u] = srcn[p + 4 * u];
        #pragma unroll
        for (int u = 0; u < 4; u++) dst[16 + p + 4 * u] = srcj[p + 4 * u];
        #pragma unroll
        for (int u = 0; u < 2; u++) dst[32 + p + 4 * u] = srcb[p + 4 * u];
    }

    // B prefetch (kc=0,1) issued before barrier
    bf16x8 bcur[4], bnxt[4];
    #pragma unroll
    for (int ct = 0; ct < 4; ct++)
        bcur[ct] = *(const bf16x8*)(bbase + ct * 512);
    #pragma unroll
    for (int ct = 0; ct < 4; ct++)
        bnxt[ct] = *(const bf16x8*)(bbase + 8192 + ct * 512);

    __syncthreads();

    #pragma unroll
    for (int rt = 0; rt < 4; rt++)
        #pragma unroll
        for (int ct = 0; ct < 4; ct++) acc[rt][ct] = (f32x4)0.f;

    const unsigned short* abase = a_tile + m16 * TSTR + q * 8;

    #pragma unroll
    for (int kc = 0; kc < KP / 32; kc++) {
        bf16x8 a[4], b2[4];
        if (kc < KP / 32 - 2) {
            #pragma unroll
            for (int ct = 0; ct < 4; ct++)
                b2[ct] = *(const bf16x8*)(bbase + (kc + 2) * 8192 + ct * 512);
        }
        #pragma unroll
        for (int rt = 0; rt < 4; rt++)
            a[rt] = *(const bf16x8*)(abase + rt * 16 * TSTR + kc * 32);
        #pragma unroll
        for (int rt = 0; rt < 4; rt++)
            #pragma unroll
            for (int ct = 0; ct < 4; ct++)
                acc[rt][ct] = __builtin_amdgcn_mfma_f32_16x16x32_bf16(
                    a[rt], bcur[ct], acc[rt][ct], 0, 0, 0);
        if (kc < KP / 32 - 1) {
            #pragma unroll
            for (int ct = 0; ct < 4; ct++) bcur[ct] = bnxt[ct];
        }
        if (kc < KP / 32 - 2) {
            #pragma unroll
            for (int ct = 0; ct < 4; ct++) bnxt[ct] = b2[ct];
        }
    }
}

// ---------------- MFMA GEMM (R0 monolith): g_t stores + bn stats; zeroes part2 ----------------
__global__ __launch_bounds__(256, 3) void gemm_mfma_kernel(
    const unsigned short* __restrict__ af16, const unsigned short* __restrict__ nbr16,
    const int* __restrict__ idx, const unsigned short* __restrict__ Wb,
    const float* __restrict__ bias_a, const float* __restrict__ bias_b,
    unsigned short* __restrict__ g_t, float* __restrict__ part1,
    float* __restrict__ part2, int NM, int M)
{
    __shared__ __align__(16) unsigned short a_tile[ROWS * TSTR];
    int t = threadIdx.x;
    const int e0 = blockIdx.x * ROWS;

    if (blockIdx.x < 16) part2[blockIdx.x * 256 + t] = 0.f;   // zero bn2 partials for gate

    f32x4 acc[4][4];
    gemm_core(af16, nbr16, idx, Wb, a_tile, e0, M, t, acc);

    const int l = t & 63, w = t >> 6, m16 = l & 15, q = l >> 4;
    float* pp = part1 + (size_t)(blockIdx.x & (P1 - 1)) * 512;
    #pragma unroll
    for (int ct = 0; ct < 4; ct++) {
        int col = w * 64 + ct * 16 + m16;
        float bias = (col < 128) ? bias_a[col] : bias_b[col - 128];
        float ps = 0.f, pq = 0.f;
        #pragma unroll
        for (int rt = 0; rt < 4; rt++) {
            float v0 = acc[rt][ct][0] + bias;
            float v1 = acc[rt][ct][1] + bias;
            float v2 = acc[rt][ct][2] + bias;
            float v3 = acc[rt][ct][3] + bias;
            ps += (v0 + v1) + (v2 + v3);
            pq += (v0 * v0 + v1 * v1) + (v2 * v2 + v3 * v3);
            uint2 pk;
            pk.x = pack2(v0, v1);
            pk.y = pack2(v2, v3);
            *(uint2*)(g_t + (size_t)col * NM + e0 + rt * 16 + q * 4) = pk;
        }
        ps += __shfl_xor(ps, 16); ps += __shfl_xor(ps, 32);
        pq += __shfl_xor(pq, 16); pq += __shfl_xor(pq, 32);
        if (q == 0) {
            atomicAdd(&pp[col], ps);
            atomicAdd(&pp[256 + col], pq);
        }
    }
}

// ---------------- gate v2: fused bn1-finalize + gate + bn2 stats, uint4 loads ----------------
// Block = 128 atoms (ab) x 16 channel-pairs (pg). Lane owns 2 atoms per pair:
// 3x uint4 (48B, aligned) per column. LDS tile [128][17] -> coalesced summed writes,
// no atomics on summed (each (atom, ch) owned by exactly one block).
__global__ __launch_bounds__(256) void gate_kernel(
    const unsigned short* __restrict__ gt, const float* __restrict__ part1,
    const float* __restrict__ gamma, const float* __restrict__ beta,
    float* __restrict__ summed, float* __restrict__ part2,
    float cnt1, int N, int NM)
{
    __shared__ float affA[32], affC[32];
    __shared__ float ls[128 * 17];
    int t = threadIdx.x, w = t >> 6, l = t & 63;
    int ab = blockIdx.x >> 3, pg = blockIdx.x & 7;

    // ---- bn1 finalize for this block's 32 channels ----
    if (t < 32) {
        int ch = (t < 16) ? (pg * 16 + t) : (128 + pg * 16 + (t - 16));
        float s = 0.f, qq = 0.f;
        #pragma unroll 8
        for (int p = 0; p < P1; p++) {
            s += part1[(size_t)p * 512 + ch];
            qq += part1[(size_t)p * 512 + 256 + ch];
        }
        float mean = s / cnt1;
        float var = fmaxf(qq / cnt1 - mean * mean, 0.f);
        float a = gamma[ch] * rsqrtf(var + 1e-5f);
        affA[t] = a;
        affC[t] = beta[ch] - mean * a;
    }
    __syncthreads();

    int n0 = ab * 128 + 2 * l;
    bool a0 = n0 < N, a1 = (n0 + 1) < N;
    float* pp = part2 + (size_t)(blockIdx.x & (P2 - 1)) * 256;

    #pragma unroll
    for (int pi = 0; pi < 4; pi++) {
        int plocal = w * 4 + pi;
        int chf = pg * 16 + plocal;
        float aF = affA[plocal],      cF = affC[plocal];
        float aC = affA[16 + plocal], cC = affC[16 + plocal];
        float s0 = 0.f, s1 = 0.f;
        if (a0) {
            const uint4* F = (const uint4*)(gt + (size_t)chf * NM + (size_t)n0 * 12);
            const uint4* C = (const uint4*)(gt + (size_t)(chf + 128) * NM + (size_t)n0 * 12);
            uint4 f0 = F[0], f1 = F[1], f2 = F[2];
            uint4 c0 = C[0], c1 = C[1], c2 = C[2];
            s0 = gpair(f0.x, c0.x, aF, cF, aC, cC) + gpair(f0.y, c0.y, aF, cF, aC, cC)
               + gpair(f0.z, c0.z, aF, cF, aC, cC) + gpair(f0.w, c0.w, aF, cF, aC, cC)
               + gpair(f1.x, c1.x, aF, cF, aC, cC) + gpair(f1.y, c1.y, aF, cF, aC, cC);
            s1 = gpair(f1.z, c1.z, aF, cF, aC, cC) + gpair(f1.w, c1.w, aF, cF, aC, cC)
               + gpair(f2.x, c2.x, aF, cF, aC, cC) + gpair(f2.y, c2.y, aF, cF, aC, cC)
               + gpair(f2.z, c2.z, aF, cF, aC, cC) + gpair(f2.w, c2.w, aF, cF, aC, cC);
            if (!a1) s1 = 0.f;
            ls[(2 * l) * 17 + plocal] = s0;
            if (a1) ls[(2 * l + 1) * 17 + plocal] = s1;
        }
        float sr = s0 + s1;
        float qr = s0 * s0 + s1 * s1;
        #pragma unroll
        for (int sft = 32; sft > 0; sft >>= 1) {
            sr += __shfl_xor(sr, sft);
            qr += __shfl_xor(qr, sft);
        }
        if (l == 0) {
            atomicAdd(&pp[chf], sr);
            atomicAdd(&pp[128 + chf], qr);
        }
    }
    __syncthreads();

    // ---- coalesced writeback: 16 consecutive floats per atom ----
    for (int i = t; i < 128 * 16; i += 256) {
        int a = i >> 4, c = i & 15;
        int n = ab * 128 + a;
        if (n < N) summed[(size_t)n * AFEA + pg * 16 + c] = ls[a * 17 + c];
    }
}

// ---------------- residual update: fused bn2-finalize + af = leaky(af + bn2(summed)) ----------------
// Also re-zeroes part1 for the next gemm (gate already consumed it; stream-order safe).
__global__ __launch_bounds__(256) void afup_kernel(
    float* __restrict__ af, unsigned short* __restrict__ af16,
    const float* __restrict__ summed, const float* __restrict__ part2,
    const float* __restrict__ gamma2, const float* __restrict__ beta2,
    float* __restrict__ part1, float cnt2, int total)
{
    __shared__ float a2s[128], c2s[128];
    int t = threadIdx.x;
    if (blockIdx.x < 128) part1[blockIdx.x * 256 + t] = 0.f;
    if (t < 128) {
        float s = 0.f, qq = 0.f;
        #pragma unroll
        for (int p = 0; p < P2; p++) {
            s += part2[(size_t)p * 256 + t];
            qq += part2[(size_t)p * 256 + 128 + t];
        }
        float mean = s / cnt2;
        float var = fmaxf(qq / cnt2 - mean * mean, 0.f);
        float a = gamma2[t] * rsqrtf(var + 1e-5f);
        a2s[t] = a;
        c2s[t] = beta2[t] - mean * a;
    }
    __syncthreads();
    int o = t & 127;
    float a2 = a2s[o], c2 = c2s[o];
    int base = blockIdx.x * 2048 + t;
    #pragma unroll
    for (int k = 0; k < 8; k++) {
        int i = base + k * 256;
        if (i < total) {
            float v = af[i] + a2 * summed[i] + c2;
            v = (v >= 0.f) ? v : 0.01f * v;
            af[i] = v;
            af16[i] = bfbits(v);
        }
    }
}

// ---------------- head: fused bn-finalize + both heads; thread owns 2 bonds ----------------
__global__ __launch_bounds__(256) void head_kernel(
    const unsigned short* __restrict__ gt, const float* __restrict__ part1,
    const float* __restrict__ dbg, const float* __restrict__ cbg,
    const float* __restrict__ dbb, const float* __restrict__ cbb,
    const float* __restrict__ w2d, const float* __restrict__ b2d,
    const float* __restrict__ w2c, const float* __restrict__ b2c,
    const float* __restrict__ pos, const float* __restrict__ off,
    const float* __restrict__ cells, const int* __restrict__ idx,
    float* __restrict__ out, float cnt1, int NM, int M)
{
    __shared__ float a_s[256], c_s[256], w_s[256];
    int t = threadIdx.x;
    {
        float s = 0.f, qq = 0.f;
        #pragma unroll 8
        for (int p = 0; p < P1; p++) {
            s += part1[(size_t)p * 512 + t];
            qq += part1[(size_t)p * 512 + 256 + t];
        }
        float mean = s / cnt1;
        float var = fmaxf(qq / cnt1 - mean * mean, 0.f);
        float g  = (t < 128) ? dbg[t] : cbg[t - 128];
        float be = (t < 128) ? dbb[t] : cbb[t - 128];
        float a = g * rsqrtf(var + 1e-5f);
        a_s[t] = a;
        c_s[t] = be - mean * a;
        w_s[t] = (t < 128) ? w2d[t] : w2c[t - 128];
    }
    __syncthreads();

    int e = blockIdx.x * 512 + t * 2;
    if (e >= NM) return;
    float sd0 = 0.f, sd1 = 0.f, sc0 = 0.f, sc1 = 0.f;
    #pragma unroll 4
    for (int ch = 0; ch < 128; ch++) {
        unsigned int u = *(const unsigned int*)(gt + (size_t)ch * NM + e);
        float a = a_s[ch], c = c_s[ch], wv = w_s[ch];
        sd0 += leakyf(fmaf(a, blo(u), c)) * wv;
        sd1 += leakyf(fmaf(a, bhi(u), c)) * wv;
    }
    #pragma unroll 4
    for (int ch = 128; ch < 256; ch++) {
        unsigned int u = *(const unsigned int*)(gt + (size_t)ch * NM + e);
        float a = a_s[ch], c = c_s[ch], wv = w_s[ch];
        sc0 += softplus_fast(fmaf(a, blo(u), c)) * wv;
        sc1 += softplus_fast(fmaf(a, bhi(u), c)) * wv;
    }
    float dist[2];
    #pragma unroll
    for (int h = 0; h < 2; h++) {
        int eb = e + h;
        int n = eb / M;
        int j = idx[eb];
        float o0 = off[(size_t)eb * 3 + 0];
        float o1 = off[(size_t)eb * 3 + 1];
        float o2 = off[(size_t)eb * 3 + 2];
        float d0 = o0 * cells[0] + o1 * cells[3] + o2 * cells[6] + pos[(size_t)j * 3 + 0] - pos[(size_t)n * 3 + 0];
        float d1 = o0 * cells[1] + o1 * cells[4] + o2 * cells[7] + pos[(size_t)j * 3 + 1] - pos[(size_t)n * 3 + 1];
        float d2 = o0 * cells[2] + o1 * cells[5] + o2 * cells[8] + pos[(size_t)j * 3 + 2] - pos[(size_t)n * 3 + 2];
        dist[h] = sqrtf(d0 * d0 + d1 * d1 + d2 * d2 + 1e-12f);
    }
    float bd = b2d[0], bc = b2c[0];
    float4 o4;
    o4.x = leakyf(sd0 + bd + dist[0]);
    o4.y = softplus_fast(sc0 + bc);
    o4.z = leakyf(sd1 + bd + dist[1]);
    o4.w = softplus_fast(sc1 + bc);
    *(float4*)(out + (size_t)e * 2) = o4;
}

extern "C" void kernel_launch(void* const* d_in, const int* in_sizes, int n_in,
                              void* d_out, int out_size, void* d_ws, size_t ws_size,
                              hipStream_t stream) {
    const float* atom_fea   = (const float*)d_in[0];
    const float* nbr_fea    = (const float*)d_in[1];
    const float* nbr_off    = (const float*)d_in[2];
    const float* atom_pos   = (const float*)d_in[3];
    const float* cells      = (const float*)d_in[4];
    const int*   idx        = (const int*)d_in[5];
    const float* emb_W      = (const float*)d_in[6];
    const float* emb_b      = (const float*)d_in[7];
    const float* convs_W    = (const float*)d_in[8];
    const float* convs_b    = (const float*)d_in[9];
    const float* bn1g       = (const float*)d_in[10];
    const float* bn1b       = (const float*)d_in[11];
    const float* bn2g       = (const float*)d_in[12];
    const float* bn2b       = (const float*)d_in[13];
    const float* dist_W     = (const float*)d_in[14];
    const float* dist_b     = (const float*)d_in[15];
    const float* dist_bn_g  = (const float*)d_in[16];
    const float* dist_bn_b  = (const float*)d_in[17];
    const float* dist2_W    = (const float*)d_in[18];
    const float* dist2_b    = (const float*)d_in[19];
    const float* const_W    = (const float*)d_in[20];
    const float* const_b    = (const float*)d_in[21];
    const float* const_bn_g = (const float*)d_in[22];
    const float* const_bn_b = (const float*)d_in[23];
    const float* const2_W   = (const float*)d_in[24];
    const float* const2_b   = (const float*)d_in[25];

    const int N  = in_sizes[0] / 92;
    const int M  = in_sizes[5] / N;
    const int NM = N * M;

    char* ws = (char*)d_ws;
    size_t off = 0;
    float* af             = (float*)(ws + off); off += (size_t)N * AFEA * 4;
    float* summed         = (float*)(ws + off); off += (size_t)N * AFEA * 4;
    unsigned short* af16  = (unsigned short*)(ws + off); off += (size_t)N * AFEA * 2;
    unsigned short* Wb4   = (unsigned short*)(ws + off); off += (size_t)4 * 256 * KP * 2;
    float* part1          = (float*)(ws + off); off += (size_t)P1 * 512 * 4;
    float* part2          = (float*)(ws + off); off += (size_t)P2 * 256 * 4;
    unsigned short* g_t   = (unsigned short*)(ws + off); off += (size_t)NM * 256 * 2;
    unsigned short* nbr16 = (unsigned short*)(ws + off); off += (size_t)NM * 64 * 2;

    const int NPART = P1 * 512 + P2 * 256;   // part1+part2 contiguous

    prep_all_kernel<<<(4 * KP * 256 + 255) / 256, 256, 0, stream>>>(
        convs_W, dist_W, const_W, Wb4, part1, NPART);
    nbr16_kernel<<<(NM * 64 + 255) / 256, 256, 0, stream>>>(nbr_fea, nbr16, NM);
    embed_kernel<<<(N + 15) / 16, 256, 0, stream>>>(atom_fea, emb_W, emb_b, af, af16, N);

    const int gblocks = NM / ROWS;
    const int gateblocks = ((N + 127) / 128) * 8;

    for (int i = 0; i < 3; i++) {
        const unsigned short* Wbi = Wb4 + (size_t)i * KP * 256;
        const float* cb = convs_b + (size_t)i * 256;
        gemm_mfma_kernel<<<gblocks, 256, 0, stream>>>(
            af16, nbr16, idx, Wbi, cb, cb + 128, g_t, part1, part2, NM, M);
        gate_kernel<<<gateblocks, 256, 0, stream>>>(
            g_t, part1, bn1g + (size_t)i * 256, bn1b + (size_t)i * 256,
            summed, part2, (float)NM, N, NM);
        afup_kernel<<<(N * AFEA + 2047) / 2048, 256, 0, stream>>>(
            af, af16, summed, part2, bn2g + (size_t)i * 128, bn2b + (size_t)i * 128,
            part1, (float)N, N * AFEA);
    }

    // heads: fused 297->256 GEMM (cols 0..127 dist, 128..255 const)
    {
        gemm_mfma_kernel<<<gblocks, 256, 0, stream>>>(
            af16, nbr16, idx, Wb4 + (size_t)3 * KP * 256, dist_b, const_b,
            g_t, part1, part2, NM, M);
        head_kernel<<<(NM + 511) / 512, 256, 0, stream>>>(
            g_t, part1, dist_bn_g, const_bn_g, dist_bn_b, const_bn_b,
            dist2_W, dist2_b, const2_W, const2_b,
            atom_pos, nbr_off, cells, idx, (float*)d_out, (float)NM, NM, M);
    }
}

// Round 6
// 605.108 us; speedup vs baseline: 1.2389x; 1.0999x over previous
//
#include <hip/hip_runtime.h>
#include <hip/hip_bf16.h>
#include <math.h>

typedef __hip_bfloat16 bf16;

#define AFEA 128          // atom_fea_len
#define NBRF 41           // nbr_fea_len
#define IN2 297           // 2A + NBR
#define KP 320            // MFMA-padded K (10 chunks of 32)
#define TSTR 328          // LDS A-tile row stride in shorts (R0-proven pad)
#define TSTRE 104         // embed LDS row stride in shorts (96 + 8 pad; 13x16B units)
#define ROWS 64           // A-tile rows
#define P1 64             // bn1 stat partial copies
#define P2 16             // bn2 stat partial copies
#define WBE_OFF (4 * KP * 256)   // offset (shorts) of embed W-pack inside Wb4
#define WBE_SZ (3 * 128 * 32)    // embed W-pack size in shorts

typedef __attribute__((ext_vector_type(8))) short bf16x8;   // MFMA A/B frag
typedef __attribute__((ext_vector_type(4))) float f32x4;    // MFMA C/D frag

__device__ __forceinline__ unsigned short bfbits(float x) {
    bf16 h = __float2bfloat16(x);
    return *(unsigned short*)&h;
}
__device__ __forceinline__ unsigned int pack2(float x, float y) {
    return (unsigned int)bfbits(x) | ((unsigned int)bfbits(y) << 16);
}
__device__ __forceinline__ float blo(unsigned int u) { return __uint_as_float(u << 16); }
__device__ __forceinline__ float bhi(unsigned int u) { return __uint_as_float(u & 0xffff0000u); }
__device__ __forceinline__ float leakyf(float x) { return x >= 0.f ? x : 0.01f * x; }
// v_rcp_f32-based sigmoid: avoids the full-precision div sequence (no fast-math flags)
__device__ __forceinline__ float sigmoid_fast(float x) {
    return __builtin_amdgcn_rcpf(1.f + __expf(-x));
}
__device__ __forceinline__ float softplus_fast(float x) {
    return fmaxf(x, 0.f) + __logf(1.f + __expf(-fabsf(x)));
}

// gated contribution of 2 bonds packed in (fu, cu): sigmoid(bn(filter)) * leaky(bn(core))
__device__ __forceinline__ float gpair(unsigned int fu, unsigned int cu,
                                       float aF, float cF, float aC, float cC) {
    float r = sigmoid_fast(fmaf(aF, blo(fu), cF)) * leakyf(fmaf(aC, blo(cu), cC));
    r += sigmoid_fast(fmaf(aF, bhi(fu), cF)) * leakyf(fmaf(aC, bhi(cu), cC));
    return r;
}

// ---------------- nbr_fea (f32 [NM][41]) -> nbr16 (bf16 [NM][64], zero-padded) ----------------
__global__ void nbr16_kernel(const float* __restrict__ nbr, unsigned short* __restrict__ nbr16,
                             int NM)
{
    int i = blockIdx.x * blockDim.x + threadIdx.x;
    if (i >= NM * 64) return;
    int k = i & 63, e = i >> 6;
    nbr16[i] = (k < NBRF) ? bfbits(nbr[(size_t)e * NBRF + k]) : 0;
}

// ---------------- embedding via MFMA: af = atom_fea @ emb_W.T + emb_b ----------------
// 64-atom x 128-col tile, K = 92 padded to 96 (3 chunks). Same fragment geometry as
// gemm_core. Replaces the scalar-LDS-read embed (2 ds_read_b32/FMA, ~40-70us hidden).
__global__ __launch_bounds__(256) void embed_mfma_kernel(
    const float* __restrict__ xf, const unsigned short* __restrict__ WbE,
    const float* __restrict__ b, float* __restrict__ af,
    unsigned short* __restrict__ af16, int N)
{
    __shared__ __align__(16) unsigned short ls[64 * TSTRE];
    int t = threadIdx.x;
    const int e0 = blockIdx.x * 64;
    const int l = t & 63, w = t >> 6, m16 = l & 15, q = l >> 4;

    // stage: 4 threads/row, f32 -> bf16, zero-pad k 92..95
    {
        int r = t >> 2, p = t & 3;
        int n = e0 + r;
        const float* src = xf + (size_t)n * 92;
        unsigned short* dst = ls + r * TSTRE;
        #pragma unroll
        for (int u = 0; u < 6; u++) {
            int k0 = p * 24 + u * 4;
            if (k0 < 92) {
                float4 v = (n < N) ? *(const float4*)(src + k0)
                                   : make_float4(0.f, 0.f, 0.f, 0.f);
                ushort4 h;
                h.x = bfbits(v.x); h.y = bfbits(v.y);
                h.z = bfbits(v.z); h.w = bfbits(v.w);
                *(ushort4*)(dst + k0) = h;
            }
        }
        if (p == 3) {
            ushort4 z = {0, 0, 0, 0};
            *(ushort4*)(dst + 92) = z;
        }
    }

    const unsigned short* bbase = WbE + (size_t)(w * 32 + m16) * 32 + q * 8;
    __syncthreads();

    f32x4 acc[4][2];
    #pragma unroll
    for (int rt = 0; rt < 4; rt++)
        #pragma unroll
        for (int ct = 0; ct < 2; ct++) acc[rt][ct] = (f32x4)0.f;

    const unsigned short* abase = ls + m16 * TSTRE + q * 8;

    #pragma unroll
    for (int kc = 0; kc < 3; kc++) {
        bf16x8 a[4], bfr[2];
        #pragma unroll
        for (int ct = 0; ct < 2; ct++)
            bfr[ct] = *(const bf16x8*)(bbase + kc * 4096 + ct * 512);
        #pragma unroll
        for (int rt = 0; rt < 4; rt++)
            a[rt] = *(const bf16x8*)(abase + rt * 16 * TSTRE + kc * 32);
        #pragma unroll
        for (int rt = 0; rt < 4; rt++)
            #pragma unroll
            for (int ct = 0; ct < 2; ct++)
                acc[rt][ct] = __builtin_amdgcn_mfma_f32_16x16x32_bf16(
                    a[rt], bfr[ct], acc[rt][ct], 0, 0, 0);
    }

    #pragma unroll
    for (int ct = 0; ct < 2; ct++) {
        int col = w * 32 + ct * 16 + m16;
        float bias = b[col];
        #pragma unroll
        for (int rt = 0; rt < 4; rt++) {
            #pragma unroll
            for (int j = 0; j < 4; j++) {
                int n = e0 + rt * 16 + q * 4 + j;
                if (n < N) {
                    float v = acc[rt][ct][j] + bias;
                    af[(size_t)n * AFEA + col] = v;
                    af16[(size_t)n * AFEA + col] = bfbits(v);
                }
            }
        }
    }
}

// ---------------- prep_all: zero stat partials + build 4 Wb sets + embed W-pack ----------------
// Wb4 layout: [set 0..3][KP/32][256][32] bf16, then WbE [3][128][32] at WBE_OFF.
__global__ void prep_all_kernel(const float* __restrict__ convs_W,
                                const float* __restrict__ dist_W,
                                const float* __restrict__ const_W,
                                const float* __restrict__ emb_W,
                                unsigned short* __restrict__ Wb4,
                                float* __restrict__ zbuf, int nz)
{
    int i = blockIdx.x * blockDim.x + threadIdx.x;
    if (i < nz) zbuf[i] = 0.f;
    if (i >= WBE_OFF + WBE_SZ) return;
    if (i >= WBE_OFF) {
        int r2 = i - WBE_OFF;
        int t32 = r2 & 31, c = (r2 >> 5) & 127, kc = r2 >> 12;
        int k = kc * 32 + t32;
        Wb4[i] = bfbits((k < 92) ? emb_W[(size_t)c * 92 + k] : 0.f);
        return;
    }
    int s = i / (KP * 256);
    int r = i - s * (KP * 256);
    int t32 = r & 31;
    int c = (r >> 5) & 255;
    int kc = r >> 13;
    int k = kc * 32 + t32;
    float v = 0.f;
    if (k < IN2) {
        if (s < 3) v = convs_W[((size_t)s * 256 + c) * IN2 + k];
        else       v = (c < 128) ? dist_W[(size_t)c * IN2 + k]
                                 : const_W[(size_t)(c - 128) * IN2 + k];
    }
    Wb4[i] = bfbits(v);
}

// ---------------- shared GEMM core (R0-proven): stage A-tile, MFMA K-loop -> acc ----------------
__device__ __forceinline__ void gemm_core(
    const unsigned short* __restrict__ af16, const unsigned short* __restrict__ nbr16,
    const int* __restrict__ idx, const unsigned short* __restrict__ Wb,
    unsigned short* a_tile, int e0, int M, int t, f32x4 (&acc)[4][4])
{
    const int l = t & 63, w = t >> 6;
    const int m16 = l & 15, q = l >> 4;
    const unsigned short* bbase = Wb + (size_t)(w * 64 + m16) * 32 + q * 8;

    // stage A-tile: 64 rows, 4 threads/row, all 16B vector ops
    {
        int row = t >> 2, p = t & 3;
        int e = e0 + row;
        int n = e / M;
        int j = idx[e];
        const uint4* srcn = (const uint4*)(af16 + (size_t)n * AFEA);
        const uint4* srcj = (const uint4*)(af16 + (size_t)j * AFEA);
        const uint4* srcb = (const uint4*)(nbr16 + (size_t)e * 64);
        uint4* dst = (uint4*)(a_tile + row * TSTR);
        #pragma unroll
        for (int u = 0; u < 4; u++) dst[p + 4 * u] = srcn[p + 4 * u];
        #pragma unroll
        for (int u = 0; u < 4; u++) dst[16 + p + 4 * u] = srcj[p + 4 * u];
        #pragma unroll
        for (int u = 0; u < 2; u++) dst[32 + p + 4 * u] = srcb[p + 4 * u];
    }

    // B prefetch (kc=0,1) issued before barrier
    bf16x8 bcur[4], bnxt[4];
    #pragma unroll
    for (int ct = 0; ct < 4; ct++)
        bcur[ct] = *(const bf16x8*)(bbase + ct * 512);
    #pragma unroll
    for (int ct = 0; ct < 4; ct++)
        bnxt[ct] = *(const bf16x8*)(bbase + 8192 + ct * 512);

    __syncthreads();

    #pragma unroll
    for (int rt = 0; rt < 4; rt++)
        #pragma unroll
        for (int ct = 0; ct < 4; ct++) acc[rt][ct] = (f32x4)0.f;

    const unsigned short* abase = a_tile + m16 * TSTR + q * 8;

    #pragma unroll
    for (int kc = 0; kc < KP / 32; kc++) {
        bf16x8 a[4], b2[4];
        if (kc < KP / 32 - 2) {
            #pragma unroll
            for (int ct = 0; ct < 4; ct++)
                b2[ct] = *(const bf16x8*)(bbase + (kc + 2) * 8192 + ct * 512);
        }
        #pragma unroll
        for (int rt = 0; rt < 4; rt++)
            a[rt] = *(const bf16x8*)(abase + rt * 16 * TSTR + kc * 32);
        #pragma unroll
        for (int rt = 0; rt < 4; rt++)
            #pragma unroll
            for (int ct = 0; ct < 4; ct++)
                acc[rt][ct] = __builtin_amdgcn_mfma_f32_16x16x32_bf16(
                    a[rt], bcur[ct], acc[rt][ct], 0, 0, 0);
        if (kc < KP / 32 - 1) {
            #pragma unroll
            for (int ct = 0; ct < 4; ct++) bcur[ct] = bnxt[ct];
        }
        if (kc < KP / 32 - 2) {
            #pragma unroll
            for (int ct = 0; ct < 4; ct++) bnxt[ct] = b2[ct];
        }
    }
}

// ---------------- MFMA GEMM (R0 monolith): g_t stores + bn stats; zeroes part2 ----------------
__global__ __launch_bounds__(256, 3) void gemm_mfma_kernel(
    const unsigned short* __restrict__ af16, const unsigned short* __restrict__ nbr16,
    const int* __restrict__ idx, const unsigned short* __restrict__ Wb,
    const float* __restrict__ bias_a, const float* __restrict__ bias_b,
    unsigned short* __restrict__ g_t, float* __restrict__ part1,
    float* __restrict__ part2, int NM, int M)
{
    __shared__ __align__(16) unsigned short a_tile[ROWS * TSTR];
    int t = threadIdx.x;
    const int e0 = blockIdx.x * ROWS;

    if (blockIdx.x < 16) part2[blockIdx.x * 256 + t] = 0.f;   // zero bn2 partials for gate

    f32x4 acc[4][4];
    gemm_core(af16, nbr16, idx, Wb, a_tile, e0, M, t, acc);

    const int l = t & 63, w = t >> 6, m16 = l & 15, q = l >> 4;
    float* pp = part1 + (size_t)(blockIdx.x & (P1 - 1)) * 512;
    #pragma unroll
    for (int ct = 0; ct < 4; ct++) {
        int col = w * 64 + ct * 16 + m16;
        float bias = (col < 128) ? bias_a[col] : bias_b[col - 128];
        float ps = 0.f, pq = 0.f;
        #pragma unroll
        for (int rt = 0; rt < 4; rt++) {
            float v0 = acc[rt][ct][0] + bias;
            float v1 = acc[rt][ct][1] + bias;
            float v2 = acc[rt][ct][2] + bias;
            float v3 = acc[rt][ct][3] + bias;
            ps += (v0 + v1) + (v2 + v3);
            pq += (v0 * v0 + v1 * v1) + (v2 * v2 + v3 * v3);
            uint2 pk;
            pk.x = pack2(v0, v1);
            pk.y = pack2(v2, v3);
            *(uint2*)(g_t + (size_t)col * NM + e0 + rt * 16 + q * 4) = pk;
        }
        ps += __shfl_xor(ps, 16); ps += __shfl_xor(ps, 32);
        pq += __shfl_xor(pq, 16); pq += __shfl_xor(pq, 32);
        if (q == 0) {
            atomicAdd(&pp[col], ps);
            atomicAdd(&pp[256 + col], pq);
        }
    }
}

// ---------------- gate v2: fused bn1-finalize + gate + bn2 stats, uint4 loads ----------------
// Block = 128 atoms (ab) x 16 channel-pairs (pg). Lane owns 2 atoms per pair:
// 3x uint4 (48B, aligned) per column. LDS tile [128][17] -> coalesced summed writes.
__global__ __launch_bounds__(256) void gate_kernel(
    const unsigned short* __restrict__ gt, const float* __restrict__ part1,
    const float* __restrict__ gamma, const float* __restrict__ beta,
    float* __restrict__ summed, float* __restrict__ part2,
    float cnt1, int N, int NM)
{
    __shared__ float affA[32], affC[32];
    __shared__ float ls[128 * 17];
    int t = threadIdx.x, w = t >> 6, l = t & 63;
    int ab = blockIdx.x >> 3, pg = blockIdx.x & 7;

    // ---- bn1 finalize for this block's 32 channels ----
    if (t < 32) {
        int ch = (t < 16) ? (pg * 16 + t) : (128 + pg * 16 + (t - 16));
        float s = 0.f, qq = 0.f;
        #pragma unroll 8
        for (int p = 0; p < P1; p++) {
            s += part1[(size_t)p * 512 + ch];
            qq += part1[(size_t)p * 512 + 256 + ch];
        }
        float mean = s / cnt1;
        float var = fmaxf(qq / cnt1 - mean * mean, 0.f);
        float a = gamma[ch] * rsqrtf(var + 1e-5f);
        affA[t] = a;
        affC[t] = beta[ch] - mean * a;
    }
    __syncthreads();

    int n0 = ab * 128 + 2 * l;
    bool a0 = n0 < N, a1 = (n0 + 1) < N;
    float* pp = part2 + (size_t)(blockIdx.x & (P2 - 1)) * 256;

    #pragma unroll
    for (int pi = 0; pi < 4; pi++) {
        int plocal = w * 4 + pi;
        int chf = pg * 16 + plocal;
        float aF = affA[plocal],      cF = affC[plocal];
        float aC = affA[16 + plocal], cC = affC[16 + plocal];
        float s0 = 0.f, s1 = 0.f;
        if (a0) {
            const uint4* F = (const uint4*)(gt + (size_t)chf * NM + (size_t)n0 * 12);
            const uint4* C = (const uint4*)(gt + (size_t)(chf + 128) * NM + (size_t)n0 * 12);
            uint4 f0 = F[0], f1 = F[1], f2 = F[2];
            uint4 c0 = C[0], c1 = C[1], c2 = C[2];
            s0 = gpair(f0.x, c0.x, aF, cF, aC, cC) + gpair(f0.y, c0.y, aF, cF, aC, cC)
               + gpair(f0.z, c0.z, aF, cF, aC, cC) + gpair(f0.w, c0.w, aF, cF, aC, cC)
               + gpair(f1.x, c1.x, aF, cF, aC, cC) + gpair(f1.y, c1.y, aF, cF, aC, cC);
            s1 = gpair(f1.z, c1.z, aF, cF, aC, cC) + gpair(f1.w, c1.w, aF, cF, aC, cC)
               + gpair(f2.x, c2.x, aF, cF, aC, cC) + gpair(f2.y, c2.y, aF, cF, aC, cC)
               + gpair(f2.z, c2.z, aF, cF, aC, cC) + gpair(f2.w, c2.w, aF, cF, aC, cC);
            if (!a1) s1 = 0.f;
            ls[(2 * l) * 17 + plocal] = s0;
            if (a1) ls[(2 * l + 1) * 17 + plocal] = s1;
        }
        float sr = s0 + s1;
        float qr = s0 * s0 + s1 * s1;
        #pragma unroll
        for (int sft = 32; sft > 0; sft >>= 1) {
            sr += __shfl_xor(sr, sft);
            qr += __shfl_xor(qr, sft);
        }
        if (l == 0) {
            atomicAdd(&pp[chf], sr);
            atomicAdd(&pp[128 + chf], qr);
        }
    }
    __syncthreads();

    // ---- coalesced writeback: 16 consecutive floats per atom ----
    for (int i = t; i < 128 * 16; i += 256) {
        int a = i >> 4, c = i & 15;
        int n = ab * 128 + a;
        if (n < N) summed[(size_t)n * AFEA + pg * 16 + c] = ls[a * 17 + c];
    }
}

// ---------------- residual update: fused bn2-finalize + af = leaky(af + bn2(summed)) ----------------
// Also re-zeroes part1 for the next gemm (gate already consumed it; stream-order safe).
__global__ __launch_bounds__(256) void afup_kernel(
    float* __restrict__ af, unsigned short* __restrict__ af16,
    const float* __restrict__ summed, const float* __restrict__ part2,
    const float* __restrict__ gamma2, const float* __restrict__ beta2,
    float* __restrict__ part1, float cnt2, int total)
{
    __shared__ float a2s[128], c2s[128];
    int t = threadIdx.x;
    if (blockIdx.x < 128) part1[blockIdx.x * 256 + t] = 0.f;
    if (t < 128) {
        float s = 0.f, qq = 0.f;
        #pragma unroll
        for (int p = 0; p < P2; p++) {
            s += part2[(size_t)p * 256 + t];
            qq += part2[(size_t)p * 256 + 128 + t];
        }
        float mean = s / cnt2;
        float var = fmaxf(qq / cnt2 - mean * mean, 0.f);
        float a = gamma2[t] * rsqrtf(var + 1e-5f);
        a2s[t] = a;
        c2s[t] = beta2[t] - mean * a;
    }
    __syncthreads();
    int o = t & 127;
    float a2 = a2s[o], c2 = c2s[o];
    int base = blockIdx.x * 2048 + t;
    #pragma unroll
    for (int k = 0; k < 8; k++) {
        int i = base + k * 256;
        if (i < total) {
            float v = af[i] + a2 * summed[i] + c2;
            v = (v >= 0.f) ? v : 0.01f * v;
            af[i] = v;
            af16[i] = bfbits(v);
        }
    }
}

// ---------------- head: fused bn-finalize + both heads; thread owns 2 bonds ----------------
__global__ __launch_bounds__(256) void head_kernel(
    const unsigned short* __restrict__ gt, const float* __restrict__ part1,
    const float* __restrict__ dbg, const float* __restrict__ cbg,
    const float* __restrict__ dbb, const float* __restrict__ cbb,
    const float* __restrict__ w2d, const float* __restrict__ b2d,
    const float* __restrict__ w2c, const float* __restrict__ b2c,
    const float* __restrict__ pos, const float* __restrict__ off,
    const float* __restrict__ cells, const int* __restrict__ idx,
    float* __restrict__ out, float cnt1, int NM, int M)
{
    __shared__ float a_s[256], c_s[256], w_s[256];
    int t = threadIdx.x;
    {
        float s = 0.f, qq = 0.f;
        #pragma unroll 8
        for (int p = 0; p < P1; p++) {
            s += part1[(size_t)p * 512 + t];
            qq += part1[(size_t)p * 512 + 256 + t];
        }
        float mean = s / cnt1;
        float var = fmaxf(qq / cnt1 - mean * mean, 0.f);
        float g  = (t < 128) ? dbg[t] : cbg[t - 128];
        float be = (t < 128) ? dbb[t] : cbb[t - 128];
        float a = g * rsqrtf(var + 1e-5f);
        a_s[t] = a;
        c_s[t] = be - mean * a;
        w_s[t] = (t < 128) ? w2d[t] : w2c[t - 128];
    }
    __syncthreads();

    int e = blockIdx.x * 512 + t * 2;
    if (e >= NM) return;
    float sd0 = 0.f, sd1 = 0.f, sc0 = 0.f, sc1 = 0.f;
    #pragma unroll 4
    for (int ch = 0; ch < 128; ch++) {
        unsigned int u = *(const unsigned int*)(gt + (size_t)ch * NM + e);
        float a = a_s[ch], c = c_s[ch], wv = w_s[ch];
        sd0 += leakyf(fmaf(a, blo(u), c)) * wv;
        sd1 += leakyf(fmaf(a, bhi(u), c)) * wv;
    }
    #pragma unroll 4
    for (int ch = 128; ch < 256; ch++) {
        unsigned int u = *(const unsigned int*)(gt + (size_t)ch * NM + e);
        float a = a_s[ch], c = c_s[ch], wv = w_s[ch];
        sc0 += softplus_fast(fmaf(a, blo(u), c)) * wv;
        sc1 += softplus_fast(fmaf(a, bhi(u), c)) * wv;
    }
    float dist[2];
    #pragma unroll
    for (int h = 0; h < 2; h++) {
        int eb = e + h;
        int n = eb / M;
        int j = idx[eb];
        float o0 = off[(size_t)eb * 3 + 0];
        float o1 = off[(size_t)eb * 3 + 1];
        float o2 = off[(size_t)eb * 3 + 2];
        float d0 = o0 * cells[0] + o1 * cells[3] + o2 * cells[6] + pos[(size_t)j * 3 + 0] - pos[(size_t)n * 3 + 0];
        float d1 = o0 * cells[1] + o1 * cells[4] + o2 * cells[7] + pos[(size_t)j * 3 + 1] - pos[(size_t)n * 3 + 1];
        float d2 = o0 * cells[2] + o1 * cells[5] + o2 * cells[8] + pos[(size_t)j * 3 + 2] - pos[(size_t)n * 3 + 2];
        dist[h] = sqrtf(d0 * d0 + d1 * d1 + d2 * d2 + 1e-12f);
    }
    float bd = b2d[0], bc = b2c[0];
    float4 o4;
    o4.x = leakyf(sd0 + bd + dist[0]);
    o4.y = softplus_fast(sc0 + bc);
    o4.z = leakyf(sd1 + bd + dist[1]);
    o4.w = softplus_fast(sc1 + bc);
    *(float4*)(out + (size_t)e * 2) = o4;
}

extern "C" void kernel_launch(void* const* d_in, const int* in_sizes, int n_in,
                              void* d_out, int out_size, void* d_ws, size_t ws_size,
                              hipStream_t stream) {
    const float* atom_fea   = (const float*)d_in[0];
    const float* nbr_fea    = (const float*)d_in[1];
    const float* nbr_off    = (const float*)d_in[2];
    const float* atom_pos   = (const float*)d_in[3];
    const float* cells      = (const float*)d_in[4];
    const int*   idx        = (const int*)d_in[5];
    const float* emb_W      = (const float*)d_in[6];
    const float* emb_b      = (const float*)d_in[7];
    const float* convs_W    = (const float*)d_in[8];
    const float* convs_b    = (const float*)d_in[9];
    const float* bn1g       = (const float*)d_in[10];
    const float* bn1b       = (const float*)d_in[11];
    const float* bn2g       = (const float*)d_in[12];
    const float* bn2b       = (const float*)d_in[13];
    const float* dist_W     = (const float*)d_in[14];
    const float* dist_b     = (const float*)d_in[15];
    const float* dist_bn_g  = (const float*)d_in[16];
    const float* dist_bn_b  = (const float*)d_in[17];
    const float* dist2_W    = (const float*)d_in[18];
    const float* dist2_b    = (const float*)d_in[19];
    const float* const_W    = (const float*)d_in[20];
    const float* const_b    = (const float*)d_in[21];
    const float* const_bn_g = (const float*)d_in[22];
    const float* const_bn_b = (const float*)d_in[23];
    const float* const2_W   = (const float*)d_in[24];
    const float* const2_b   = (const float*)d_in[25];

    const int N  = in_sizes[0] / 92;
    const int M  = in_sizes[5] / N;
    const int NM = N * M;

    char* ws = (char*)d_ws;
    size_t off = 0;
    float* af             = (float*)(ws + off); off += (size_t)N * AFEA * 4;
    float* summed         = (float*)(ws + off); off += (size_t)N * AFEA * 4;
    unsigned short* af16  = (unsigned short*)(ws + off); off += (size_t)N * AFEA * 2;
    unsigned short* Wb4   = (unsigned short*)(ws + off); off += (size_t)(WBE_OFF + WBE_SZ) * 2;
    float* part1          = (float*)(ws + off); off += (size_t)P1 * 512 * 4;
    float* part2          = (float*)(ws + off); off += (size_t)P2 * 256 * 4;
    unsigned short* g_t   = (unsigned short*)(ws + off); off += (size_t)NM * 256 * 2;
    unsigned short* nbr16 = (unsigned short*)(ws + off); off += (size_t)NM * 64 * 2;

    const int NPART = P1 * 512 + P2 * 256;   // part1+part2 contiguous

    prep_all_kernel<<<(WBE_OFF + WBE_SZ + 255) / 256, 256, 0, stream>>>(
        convs_W, dist_W, const_W, emb_W, Wb4, part1, NPART);
    nbr16_kernel<<<(NM * 64 + 255) / 256, 256, 0, stream>>>(nbr_fea, nbr16, NM);
    embed_mfma_kernel<<<(N + 63) / 64, 256, 0, stream>>>(
        atom_fea, Wb4 + WBE_OFF, emb_b, af, af16, N);

    const int gblocks = NM / ROWS;
    const int gateblocks = ((N + 127) / 128) * 8;

    for (int i = 0; i < 3; i++) {
        const unsigned short* Wbi = Wb4 + (size_t)i * KP * 256;
        const float* cb = convs_b + (size_t)i * 256;
        gemm_mfma_kernel<<<gblocks, 256, 0, stream>>>(
            af16, nbr16, idx, Wbi, cb, cb + 128, g_t, part1, part2, NM, M);
        gate_kernel<<<gateblocks, 256, 0, stream>>>(
            g_t, part1, bn1g + (size_t)i * 256, bn1b + (size_t)i * 256,
            summed, part2, (float)NM, N, NM);
        afup_kernel<<<(N * AFEA + 2047) / 2048, 256, 0, stream>>>(
            af, af16, summed, part2, bn2g + (size_t)i * 128, bn2b + (size_t)i * 128,
            part1, (float)N, N * AFEA);
    }

    // heads: fused 297->256 GEMM (cols 0..127 dist, 128..255 const)
    {
        gemm_mfma_kernel<<<gblocks, 256, 0, stream>>>(
            af16, nbr16, idx, Wb4 + (size_t)3 * KP * 256, dist_b, const_b,
            g_t, part1, part2, NM, M);
        head_kernel<<<(NM + 511) / 512, 256, 0, stream>>>(
            g_t, part1, dist_bn_g, const_bn_g, dist_bn_b, const_bn_b,
            dist2_W, dist2_b, const2_W, const2_b,
            atom_pos, nbr_off, cells, idx, (float*)d_out, (float)NM, NM, M);
    }
}